// Round 1
// baseline (599.350 us; speedup 1.0000x reference)
//
#include <hip/hip_runtime.h>
#include <hip/hip_bf16.h>

// Problem: B=32, S=4096, D=512.
// out = [att_weights (32,4096) fp32 | hidden_output (32,512) fp32]
//
// Fused flash-style pipeline:
//   wconv:  Ws -> bf16 tiled+swizzled (512 KB)
//   t:      t[b,h] = targ . Wt
//   fused:  per 128-row tile: full-h GEMM -> e, local softmax (m_L, sum_L),
//           ctx partial from the bf16 A tile resident in LDS  (src read ONCE)
//   final2: merge 32 tiles/batch: global softmax consts, att, hidden_output

typedef __attribute__((ext_vector_type(8))) short bf16x8;
typedef __attribute__((ext_vector_type(4))) float f32x4;

#define L2E 1.4426950408889634f

// packed fp32x2 -> bf16x2 (RNE); lowers to v_cvt_pk_bf16_f32 on gfx950
static __device__ __forceinline__ unsigned cvt2(float a, float b) {
    union { __hip_bfloat162 h; unsigned u; } v;
    v.h = __float22bfloat162_rn(make_float2(a, b));
    return v.u;
}
static __device__ __forceinline__ float bits2f(unsigned u) {
    union { unsigned u; float f; } x; x.u = u; return x.f;
}
static __device__ __forceinline__ void async_load16(const void* g, void* l) {
    __builtin_amdgcn_global_load_lds(
        (const __attribute__((address_space(1))) void*)g,
        (__attribute__((address_space(3))) void*)l, 16, 0, 0);
}
static __device__ __forceinline__ float fast_tanh(float x) {
    float ex = exp2f(x * 2.8853900817779268f);
    return 1.0f - 2.0f / (ex + 1.0f);
}

// ws layout (bytes):
#define WS_WBF   0L          // 512 KB  Ws bf16 tiled+swizzled
#define WS_T     524288L     // 64 KB   t (32x512 f32)
#define WS_E     589824L     // 512 KB  e (32x4096 f32)
#define WS_MST   1114112L    // 8 KB    per-tile (m_L, sum_L) x 1024
#define WS_CTXP  1122304L    // 2 MB    1024 x 512 f32 ctx partials

// ---- Ws (W[:,512:]) -> bf16, tile-contiguous + bank-swizzled ----
// tile (hx,kt): 128 rows x 32 k; position p=(r,u') stores data unit u'^((r>>1)&3)
__global__ void wconv_kernel(const float* __restrict__ W, short* __restrict__ wbf) {
    const int gid = blockIdx.x * 256 + threadIdx.x;       // [0, 32768)
    const int tile = gid >> 9, p = gid & 511;
    const int hx = tile >> 4, ktile = tile & 15;
    const int r = p >> 2, up = p & 3;
    const int u = up ^ ((r >> 1) & 3);
    const float* s = W + (long)(hx * 128 + r) * 1024 + 512 + ktile * 32 + u * 8;
    float4 v0 = *(const float4*)(s);
    float4 v1 = *(const float4*)(s + 4);
    uint4 pk;
    pk.x = cvt2(v0.x, v0.y); pk.y = cvt2(v0.z, v0.w);
    pk.z = cvt2(v1.x, v1.y); pk.w = cvt2(v1.z, v1.w);
    ((uint4*)wbf)[gid] = pk;
}

// ---- t[b,h] = sum_d targ[b,d] * W[h, d] ----
__global__ void t_kernel(const float* __restrict__ targ,
                         const float* __restrict__ W,
                         float* __restrict__ t) {
    __shared__ float tg[512];
    const int b = blockIdx.x >> 2;
    const int hbase = (blockIdx.x & 3) * 128;
    const int tid = threadIdx.x;
    tg[tid]       = targ[b * 512 + tid];
    tg[tid + 256] = targ[b * 512 + tid + 256];
    __syncthreads();
    const int lane = tid & 63, wave = tid >> 6;
    for (int h = hbase + wave; h < hbase + 128; h += 4) {
        const float* wr = W + (long)h * 1024;
        float s = 0.f;
        #pragma unroll
        for (int i = 0; i < 2; i++) {
            const int d = lane * 4 + i * 256;
            float4 wv = *(const float4*)(wr + d);
            s += wv.x * tg[d] + wv.y * tg[d + 1] + wv.z * tg[d + 2] + wv.w * tg[d + 3];
        }
        s += __shfl_xor(s, 1);  s += __shfl_xor(s, 2);  s += __shfl_xor(s, 4);
        s += __shfl_xor(s, 8);  s += __shfl_xor(s, 16); s += __shfl_xor(s, 32);
        if (lane == 0) t[b * 512 + h] = s;
    }
}

// ---- fused: full-h GEMM for 128 s-rows + local softmax + ctx partial ----
__global__ __launch_bounds__(256, 1)
void fused_kernel(const float* __restrict__ src,
                  const short* __restrict__ wbf,
                  const float* __restrict__ t,
                  const float* __restrict__ V,
                  const float* __restrict__ mask,
                  float* __restrict__ e_ws,
                  float* __restrict__ mstats,
                  float* __restrict__ ctxp) {
    // As: 128 rows x 512 k bf16 (128 KB), 16B-chunk XOR swizzle: chunk ^= (row&7)
    __shared__ __align__(16) short As[128 * 512];
    __shared__ __align__(16) short Bs[2][4096];   // double-buffered 8 KB B tiles
    __shared__ float er[2][128];
    __shared__ float pbuf[128];
    __shared__ float red[8];

    const int tid = threadIdx.x;
    const int mt  = blockIdx.x;            // 0..1023  (= b*32 + stile)
    const int b   = mt >> 5;
    const long m0 = (long)mt * 128;        // global s-row base (b*4096 + stile*128)

    const int lane = tid & 63, wave = tid >> 6;
    const int wm = wave & 1, wn = wave >> 1;
    const int lr = lane & 15, quad = lane >> 4;
    const int l7 = lr & 7;
    const int arow = tid >> 1, ah = (tid & 1) * 16;   // A staging: row, k offset

    // prologue: B tile 0 -> Bs[0]
    async_load16(wbf + tid * 8, &Bs[0][0] + tid * 8);
    async_load16(wbf + 2048 + tid * 8, &Bs[0][0] + 2048 + tid * 8);

    for (int hx = 0; hx < 4; ++hx) {
        f32x4 acc[4][4];
        #pragma unroll
        for (int i = 0; i < 4; i++)
            #pragma unroll
            for (int j = 0; j < 4; j++)
                acc[i][j] = (f32x4){0.f, 0.f, 0.f, 0.f};

        for (int kt = 0; kt < 16; ++kt) {
            const int idx = hx * 16 + kt;
            __syncthreads();               // prev reads done; drains B(idx) prefetch
            if (idx < 63) {                // prefetch next B tile (after barrier ->
                const short* cn = wbf + (long)(idx + 1) * 4096;   // flight overlaps MFMA)
                short* bd = &Bs[(idx + 1) & 1][0];
                async_load16(cn + tid * 8, bd + tid * 8);
                async_load16(cn + 2048 + tid * 8, bd + 2048 + tid * 8);
            }
            if (hx == 0) {
                // stage A k-tile: fp32 -> bf16 (HW packed cvt) -> swizzled ds_write
                const float* ap = src + (m0 + arow) * 512 + kt * 32 + ah;
                float4 v0 = *(const float4*)(ap);
                float4 v1 = *(const float4*)(ap + 4);
                float4 v2 = *(const float4*)(ap + 8);
                float4 v3 = *(const float4*)(ap + 12);
                uint4 pA, pB;
                pA.x = cvt2(v0.x, v0.y); pA.y = cvt2(v0.z, v0.w);
                pA.z = cvt2(v1.x, v1.y); pA.w = cvt2(v1.z, v1.w);
                pB.x = cvt2(v2.x, v2.y); pB.y = cvt2(v2.z, v2.w);
                pB.z = cvt2(v3.x, v3.y); pB.w = cvt2(v3.z, v3.w);
                const int c0 = kt * 4 + (tid & 1) * 2;
                const int r7 = arow & 7;
                *(uint4*)(As + arow * 512 + ((c0    ) ^ r7) * 8) = pA;
                *(uint4*)(As + arow * 512 + ((c0 + 1) ^ r7) * 8) = pB;
                __syncthreads();           // A visible to all waves
            }

            bf16x8 af[4], bfr[4];
            const short* bsrc = &Bs[idx & 1][0];
            #pragma unroll
            for (int mi = 0; mi < 4; mi++) {
                const int row = wm * 64 + mi * 16 + lr;
                af[mi] = *(const bf16x8*)(As + row * 512 + (((kt * 4 + quad) ^ l7) * 8));
            }
            #pragma unroll
            for (int ni = 0; ni < 4; ni++) {
                const int row = wn * 64 + ni * 16 + lr;
                const int q = quad ^ ((row >> 1) & 3);
                bfr[ni] = *(const bf16x8*)(bsrc + row * 32 + q * 8);
            }
            #pragma unroll
            for (int mi = 0; mi < 4; mi++)
                #pragma unroll
                for (int ni = 0; ni < 4; ni++)
                    acc[mi][ni] = __builtin_amdgcn_mfma_f32_16x16x32_bf16(
                        af[mi], bfr[ni], acc[mi][ni], 0, 0, 0);
        }

        // chunk epilogue: e partial for these 128 h  (layout as verified kernel)
        const float* trow = t + b * 512;
        float th[4], vv[4];
        #pragma unroll
        for (int ni = 0; ni < 4; ni++) {
            const int h = hx * 128 + wn * 64 + ni * 16 + lr;
            th[ni] = trow[h];
            vv[ni] = V[h];
        }
        #pragma unroll
        for (int mi = 0; mi < 4; mi++) {
            #pragma unroll
            for (int r = 0; r < 4; r++) {
                float es = 0.f;
                #pragma unroll
                for (int ni = 0; ni < 4; ni++)
                    es += fast_tanh(acc[mi][ni][r] + th[ni]) * vv[ni];
                es += __shfl_xor(es, 1);
                es += __shfl_xor(es, 2);
                es += __shfl_xor(es, 4);
                es += __shfl_xor(es, 8);
                if (lr == 0) {
                    float* slot = &er[wn][wm * 64 + mi * 16 + quad * 4 + r];
                    if (hx == 0) *slot = es; else *slot += es;   // same thread owns slot
                }
            }
        }
    }

    __syncthreads();
    // ---- block-local softmax over the 128 rows ----
    const bool valid = tid < 128;
    float myE = valid ? (er[0][tid] + er[1][tid]) : -1e30f;
    float mx = myE;
    #pragma unroll
    for (int m = 1; m <= 32; m <<= 1) mx = fmaxf(mx, __shfl_xor(mx, m));
    if (lane == 0) red[wave] = mx;
    __syncthreads();
    const float mL = fmaxf(fmaxf(red[0], red[1]), fmaxf(red[2], red[3]));
    float pv = valid ? exp2f((myE - mL) * L2E) : 0.f;
    float sv = pv;
    #pragma unroll
    for (int m = 1; m <= 32; m <<= 1) sv += __shfl_xor(sv, m);
    if (lane == 0) red[4 + wave] = sv;
    if (valid) {
        e_ws[m0 + tid] = myE;
        pbuf[tid] = pv * mask[m0 + tid];   // masked p for ctx; sum stays unmasked
    }
    if (tid == 0) mstats[mt * 2] = mL;
    __syncthreads();
    if (tid == 0) mstats[mt * 2 + 1] = red[4] + red[5] + red[6] + red[7];

    // ---- ctx partial: ctxp[mt][d] = sum_s p_s * src_bf16[s][d] (A tile in LDS) ----
    const int d0 = tid * 2;
    const int cb = d0 >> 3;                // 16B chunk column 0..63
    const int coff = d0 & 7;               // short offset within chunk
    float a0 = 0.f, a1 = 0.f;
    #pragma unroll 4
    for (int s = 0; s < 128; ++s) {
        const unsigned u = *(const unsigned*)(As + s * 512 + ((cb ^ (s & 7)) * 8) + coff);
        const float w = pbuf[s];
        a0 += w * bits2f(u << 16);
        a1 += w * bits2f(u & 0xffff0000u);
    }
    ctxp[(long)mt * 512 + d0]     = a0;
    ctxp[(long)mt * 512 + d0 + 1] = a1;
}

// ---- finalize: merge 32 tiles per batch; att + hidden_output ----
__global__ void final2_kernel(const float* __restrict__ e_ws,
                              const float* __restrict__ mstats,
                              const float* __restrict__ ctxp,
                              const float* __restrict__ mask,
                              const float* __restrict__ targ,
                              float* __restrict__ att,
                              float* __restrict__ outh) {
    const int b = blockIdx.x, tid = threadIdx.x;
    __shared__ float wL[32];
    __shared__ float bc[2];
    if (tid < 64) {
        const int lane = tid;
        float mv = -1e30f, sv = 0.f;
        if (lane < 32) {
            mv = mstats[(b * 32 + lane) * 2];
            sv = mstats[(b * 32 + lane) * 2 + 1];
        }
        float M = mv;
        #pragma unroll
        for (int m = 1; m <= 32; m <<= 1) M = fmaxf(M, __shfl_xor(M, m));
        float sc = sv * exp2f((mv - M) * L2E);
        #pragma unroll
        for (int m = 1; m <= 32; m <<= 1) sc += __shfl_xor(sc, m);
        if (lane < 32) wL[lane] = exp2f((mv - M) * L2E) / sc;
        if (lane == 0) { bc[0] = M; bc[1] = sc; }
    }
    __syncthreads();
    const float M = bc[0], invS = 1.0f / bc[1];
    #pragma unroll
    for (int i = 0; i < 16; i++) {
        const int s = i * 256 + tid;
        const long idx = (long)b * 4096 + s;
        att[idx] = exp2f((e_ws[idx] - M) * L2E) * invS * mask[idx];
    }
    #pragma unroll
    for (int dd = 0; dd < 2; dd++) {
        const int d = dd * 256 + tid;
        float a = targ[b * 512 + d];
        for (int L = 0; L < 32; L++)
            a += wL[L] * ctxp[((long)(b * 32 + L)) * 512 + d];
        outh[b * 512 + d] = a;
    }
}

extern "C" void kernel_launch(void* const* d_in, const int* in_sizes, int n_in,
                              void* d_out, int out_size, void* d_ws, size_t ws_size,
                              hipStream_t stream) {
    const float* targ = (const float*)d_in[0];
    const float* src  = (const float*)d_in[1];
    const float* mask = (const float*)d_in[2];
    const float* W    = (const float*)d_in[3];
    const float* V    = (const float*)d_in[4];

    float* att  = (float*)d_out;
    float* outh = (float*)d_out + 131072;

    char* ws = (char*)d_ws;
    short* wbf   = (short*)(ws + WS_WBF);
    float* t     = (float*)(ws + WS_T);
    float* e     = (float*)(ws + WS_E);
    float* mst   = (float*)(ws + WS_MST);
    float* ctxp  = (float*)(ws + WS_CTXP);

    wconv_kernel<<<128, 256, 0, stream>>>(W, wbf);
    t_kernel<<<128, 256, 0, stream>>>(targ, W, t);
    fused_kernel<<<1024, 256, 0, stream>>>(src, wbf, t, V, mask, e, mst, ctxp);
    final2_kernel<<<32, 256, 0, stream>>>(e, mst, ctxp, mask, targ, att, outh);
}